// Round 9
// baseline (1978.155 us; speedup 1.0000x reference)
//
#include <hip/hip_runtime.h>
#include <stdint.h>

#define TT 128
#define BB 32
#define HH 512
#define MM 4096            // T*B == S*B
#define VD 32000
#define NLB 16             // persistent LSTM blocks (one j-slice of 32 h-units each)

typedef float f32x4 __attribute__((ext_vector_type(4)));
typedef float f32x2 __attribute__((ext_vector_type(2)));
typedef short s16x8 __attribute__((ext_vector_type(8)));
typedef unsigned long long u64;

#define TAGMASK 0x0001000100010001ull

__device__ __forceinline__ ushort f2bf(float f){
  uint u = __float_as_uint(f);
  return (ushort)((u + 0x7fffu + ((u >> 16) & 1u)) >> 16);   // RTNE
}
__device__ __forceinline__ float bfl(uint v){ return __uint_as_float(v << 16); }
__device__ __forceinline__ float bfh(uint v){ return __uint_as_float(v & 0xffff0000u); }
__device__ __forceinline__ float fast_tanh(float x){
  return 1.f - 2.f / (1.f + __expf(2.f * x));   // exact at saturation, ~1e-6 mid-range
}
__device__ __forceinline__ float sigm(float x){ return 1.f / (1.f + __expf(-x)); }

// ---------------- init: h double buffer. parity0 = h(0)=0 tag0; parity1 = tag1 (stale) ----
__global__ void k_init(u64* hbuf){
  int i = blockIdx.x * 256 + threadIdx.x;
  if (i < 4096) hbuf[i] = 0ull;
  else if (i < 8192) hbuf[i] = TAGMASK;
}

// ---------------- f32 -> bf16 convert ----------------
__global__ __launch_bounds__(256) void k_cvt(const float* __restrict__ s, ushort* __restrict__ d, int n4){
  int i = blockIdx.x * 256 + threadIdx.x;
  int st = gridDim.x * 256;
  for (; i < n4; i += st){
    f32x4 v = *(const f32x4*)(s + (size_t)i * 4);
    ushort4 o; o.x = f2bf(v[0]); o.y = f2bf(v[1]); o.z = f2bf(v[2]); o.w = f2bf(v[3]);
    *(ushort4*)(d + (size_t)i * 4) = o;
  }
}

// ---------------- embedding gather -> bf16 ----------------
__global__ __launch_bounds__(128) void k_embed(const int* __restrict__ ids, const float* __restrict__ emb,
                                               ushort* __restrict__ out){
  int row = blockIdx.x, t = threadIdx.x;
  int id = ids[row];
  f32x4 v = *(const f32x4*)(emb + (size_t)id * HH + t * 4);
  ushort4 o; o.x = f2bf(v[0]); o.y = f2bf(v[1]); o.z = f2bf(v[2]); o.w = f2bf(v[3]);
  *(ushort4*)(out + (size_t)row * HH + t * 4) = o;
}

// ---------------- build concat weight [512][1024] = [We | Wd] ----------------
__global__ __launch_bounds__(128) void k_concatB(const float* __restrict__ We, const float* __restrict__ Wd,
                                                 ushort* __restrict__ Bc){
  int n = blockIdx.x, t = threadIdx.x;
  f32x4 a = *(const f32x4*)(We + (size_t)n * HH + t * 4);
  f32x4 b = *(const f32x4*)(Wd + (size_t)n * HH + t * 4);
  ushort4 oa, ob;
  oa.x = f2bf(a[0]); oa.y = f2bf(a[1]); oa.z = f2bf(a[2]); oa.w = f2bf(a[3]);
  ob.x = f2bf(b[0]); ob.y = f2bf(b[1]); ob.z = f2bf(b[2]); ob.w = f2bf(b[3]);
  *(ushort4*)(Bc + (size_t)n * 1024 + t * 4) = oa;
  *(ushort4*)(Bc + (size_t)n * 1024 + 512 + t * 4) = ob;
}
__global__ void k_bsum(const float* a, const float* b, float* o){
  int i = blockIdx.x * 256 + threadIdx.x;
  if (i < HH) o[i] = a[i] + b[i];
}

// ---------------- bf16 MFMA GEMM, C = A[M,K] * B[N,K]^T (+bias)(+tanh)(+lse partials) ----------------
template<bool BIAS, bool TANH, bool OUTBF, bool LSE>
__global__ __launch_bounds__(256) void k_gemm(const ushort* __restrict__ A, const ushort* __restrict__ Bm,
                                              const float* __restrict__ bias, void* __restrict__ Cout,
                                              int Mtot, int Ntot, int K,
                                              float* __restrict__ pbufM, float* __restrict__ pbufL){
  __shared__ __align__(16) ushort As[128 * 32];
  __shared__ __align__(16) ushort Bs[128 * 32];
  __shared__ float sMm[2][128], sMl[2][128];
  const int tid = threadIdx.x;
  const int m0 = blockIdx.y << 7, n0 = blockIdx.x << 7;
  const int wid = tid >> 6, lane = tid & 63;
  const int wm = wid >> 1, wn = wid & 1;
  const int lr = lane & 15, lg = lane >> 4;
  const int lk = lg << 3, cr = lg << 2;
  f32x4 acc[4][4];
  for (int i = 0; i < 4; ++i)
    for (int j = 0; j < 4; ++j)
      acc[i][j] = (f32x4){0.f, 0.f, 0.f, 0.f};
  const int c0 = tid, c1 = tid + 256;
  const size_t ar0 = (size_t)(m0 + (c0 >> 2)) * K + ((c0 & 3) << 3);
  const size_t ar1 = (size_t)(m0 + (c1 >> 2)) * K + ((c1 & 3) << 3);
  const size_t br0 = (size_t)(n0 + (c0 >> 2)) * K + ((c0 & 3) << 3);
  const size_t br1 = (size_t)(n0 + (c1 >> 2)) * K + ((c1 & 3) << 3);
  for (int k0 = 0; k0 < K; k0 += 32){
    __syncthreads();
    __builtin_amdgcn_global_load_lds((const __attribute__((address_space(1))) void*)(A + ar0 + k0),
                                     (__attribute__((address_space(3))) void*)(As + (c0 << 3)), 16, 0, 0);
    __builtin_amdgcn_global_load_lds((const __attribute__((address_space(1))) void*)(A + ar1 + k0),
                                     (__attribute__((address_space(3))) void*)(As + (c1 << 3)), 16, 0, 0);
    __builtin_amdgcn_global_load_lds((const __attribute__((address_space(1))) void*)(Bm + br0 + k0),
                                     (__attribute__((address_space(3))) void*)(Bs + (c0 << 3)), 16, 0, 0);
    __builtin_amdgcn_global_load_lds((const __attribute__((address_space(1))) void*)(Bm + br1 + k0),
                                     (__attribute__((address_space(3))) void*)(Bs + (c1 << 3)), 16, 0, 0);
    __syncthreads();
    s16x8 af[4], bf[4];
    #pragma unroll
    for (int f = 0; f < 4; ++f){
      af[f] = *(const s16x8*)(As + ((wm << 6) + (f << 4) + lr) * 32 + lk);
      bf[f] = *(const s16x8*)(Bs + ((wn << 6) + (f << 4) + lr) * 32 + lk);
    }
    #pragma unroll
    for (int fm = 0; fm < 4; ++fm)
      #pragma unroll
      for (int fn = 0; fn < 4; ++fn)
        acc[fm][fn] = __builtin_amdgcn_mfma_f32_16x16x32_bf16(af[fm], bf[fn], acc[fm][fn], 0, 0, 0);
  }
  float bv4[4];
  #pragma unroll
  for (int fn = 0; fn < 4; ++fn)
    bv4[fn] = BIAS ? bias[n0 + (wn << 6) + (fn << 4) + lr] : 0.f;
  float mv[16], lv[16];
  #pragma unroll
  for (int fm = 0; fm < 4; ++fm){
    #pragma unroll
    for (int r = 0; r < 4; ++r){
      const int rw = m0 + (wm << 6) + (fm << 4) + cr + r;
      float vs[4], vmax = -1e30f;
      #pragma unroll
      for (int fn = 0; fn < 4; ++fn){
        float v = acc[fm][fn][r] + bv4[fn];
        if (TANH) v = tanhf(v);
        vs[fn] = v;
        if (LSE) vmax = fmaxf(vmax, v);
        const size_t off = (size_t)rw * Ntot + (n0 + (wn << 6) + (fn << 4) + lr);
        if (OUTBF) ((ushort*)Cout)[off] = f2bf(v);
        else       ((float*)Cout)[off] = v;
      }
      if (LSE){
        float l4 = 0.f;
        #pragma unroll
        for (int fn = 0; fn < 4; ++fn) l4 += __expf(vs[fn] - vmax);
        mv[(fm << 2) + r] = vmax; lv[(fm << 2) + r] = l4;
      }
    }
  }
  if (LSE){
    #pragma unroll
    for (int q = 0; q < 16; ++q){
      #pragma unroll
      for (int off = 1; off < 16; off <<= 1){
        float m2 = __shfl_xor(mv[q], off), l2 = __shfl_xor(lv[q], off);
        float nm = fmaxf(mv[q], m2);
        lv[q] = lv[q] * __expf(mv[q] - nm) + l2 * __expf(m2 - nm);
        mv[q] = nm;
      }
    }
    float selM = -1e30f, selL = 0.f;
    #pragma unroll
    for (int q = 0; q < 16; ++q){
      selM = (lr == q) ? mv[q] : selM;
      selL = (lr == q) ? lv[q] : selL;
    }
    const int lrow = (wm << 6) + ((lr >> 2) << 4) + (lg << 2) + (lr & 3);
    sMm[wn][lrow] = selM; sMl[wn][lrow] = selL;
    __syncthreads();
    if (tid < 128){
      float ma = sMm[0][tid], mb = sMm[1][tid];
      float nm = fmaxf(ma, mb);
      float l = sMl[0][tid] * __expf(ma - nm) + sMl[1][tid] * __expf(mb - nm);
      pbufM[(size_t)(m0 + tid) * 256 + blockIdx.x] = nm;
      pbufL[(size_t)(m0 + tid) * 256 + blockIdx.x] = l;
    }
  }
}

// ---------------- persistent LSTM: 16 blocks x 512 thr, barrier-free waves ----------------
// Exchange v8: fully self-contained waves, ZERO per-step intra-block sync.
// Key fact: h(s+1)[b] depends only on h(s)[b] -> the two batch-halves (m=0/1) are
// independent recurrences, and each wave (m, jt) already polls exactly its own m-half.
// Per step per wave: poll own A-frag slice (16 x dwordx4 sc0sc1, tags in bf16 LSBs) ->
// mask -> 32 MFMAs (4 indep chains) -> intra-wave bpermute transpose -> combine ->
// one tagged u32 agent store. Gin prefetched AFTER poll-pass (off the vmcnt(0) path),
// consumed one step later. __syncthreads only around the s==128 weight restage.
// Safety (per-wave): wave passes poll(s) only if all same-m waves published h(s) =>
// their h(s-1) reads completed => overwriting the h(s-1) slot is safe; 1-bit alternating
// tag distinguishes slot occupants; cross-m waves touch disjoint slots.
__global__ __launch_bounds__(512) void k_lstm(const float* __restrict__ GinE, const float* __restrict__ GinD,
                                              const float* __restrict__ WhhE, const float* __restrict__ WhhD,
                                              u64* __restrict__ hbuf,
                                              ushort* __restrict__ encO, ushort* __restrict__ decO,
                                              ushort* __restrict__ Ac){
  __shared__ __align__(16) ushort wlds[4 * 32 * 512];  // 128 KB weights [g][j32][k512] swizzled
  const int tid = threadIdx.x;
  const int bk = blockIdx.x;
  const int J0 = bk << 5;
  const int w = tid >> 6, lane = tid & 63;
  const int m = w & 1, jt = w >> 1;
  const int lr = lane & 15, lg = lane >> 4;
  const int beta = lane >> 2, p = lane & 3, myr = beta & 3;
  const int b_own = (m << 4) + beta;
  const int j_own = J0 + (jt << 3) + (p << 1);

  float cc0 = 0.f, cc1 = 0.f;               // 2 cell states per lane
  const int sgb = (lane & 48) + ((lane & 3) << 1);
  const int ad_l0 = sgb << 2, ad_l1 = (sgb + 1) << 2;
  const int ad_h0 = (sgb + 8) << 2, ad_h1 = (sgb + 9) << 2;
  const char* wrow0 = (const char*)wlds + ((((lr >> 3) << 5) + (jt << 3) + (lr & 7)) << 10);
  const char* wrow1 = wrow0 + (64 << 10);
  const int swz = (lr & 7) << 4;

  auto stageW = [&](const float* Whh){
    const int rr = tid >> 2, kq = tid & 3;
    const int gg = rr >> 5, jl = rr & 31;
    const float* src = Whh + (size_t)((gg << 9) + J0 + jl) * 512 + (kq << 7);
    char* dstrow = (char*)wlds + (size_t)(((gg << 5) + jl) << 10);
    #pragma unroll
    for (int i = 0; i < 16; ++i){
      f32x4 wa = *(const f32x4*)(src + (i << 3));
      f32x4 wc = *(const f32x4*)(src + (i << 3) + 4);
      uint4 pk;
      pk.x = ((uint)f2bf(wa[1]) << 16) | f2bf(wa[0]);
      pk.y = ((uint)f2bf(wa[3]) << 16) | f2bf(wa[2]);
      pk.z = ((uint)f2bf(wc[1]) << 16) | f2bf(wc[0]);
      pk.w = ((uint)f2bf(wc[3]) << 16) | f2bf(wc[2]);
      *(uint4*)(dstrow + ((((kq << 4) + i) << 4) ^ ((jl & 7) << 4))) = pk;
    }
  };

  f32x2 nxi, nxf, nxg, nxo;                 // Gin pipeline register (holds Gin(s) at step s poll)
  { const float* gp = GinE + (size_t)b_own * 2048 + j_own;
    nxi = *(const f32x2*)(gp);        nxf = *(const f32x2*)(gp + 512);
    nxg = *(const f32x2*)(gp + 1024); nxo = *(const f32x2*)(gp + 1536); }
  stageW(WhhE);
  __syncthreads();

  for (int s = 0; s < 256; ++s){
    const int ph = s >> 7, t = s & 127;
    if (s == 128){
      __syncthreads();                      // all waves done with encoder weights
      stageW(WhhD);
      __syncthreads();                      // decoder weights ready
    }
    // ---- poll-load own A-frag slice of h(s); vmcnt(0) also drains last step's Gin prefetch ----
    const uint pat = ((s >> 1) & 1) ? 0x00010001u : 0u;
    const char* hp = (const char*)hbuf + ((s & 1) << 15) + (m << 14) + (lg << 8) + (lr << 4);
    uint4 vv[16];
    for (;;){
      #pragma unroll
      for (int ks = 0; ks < 16; ++ks)
        asm volatile("global_load_dwordx4 %0, %1, off sc0 sc1"
                     : "=v"(vv[ks]) : "v"(hp + (ks << 10)) : "memory");
      asm volatile("s_waitcnt vmcnt(0)" ::: "memory");
      __builtin_amdgcn_sched_barrier(0);
      uint bad = 0u;
      #pragma unroll
      for (int ks = 0; ks < 16; ++ks)
        bad |= (vv[ks].x ^ pat) | (vv[ks].y ^ pat) | (vv[ks].z ^ pat) | (vv[ks].w ^ pat);
      if (__all((bad & 0x00010001u) == 0u)) break;
    }
    // ---- Gin(s) now in nx*; rotate and prefetch Gin(s+1) (overlaps MFMA/combine) ----
    const float gi0 = nxi[0], gi1 = nxi[1], gf0 = nxf[0], gf1 = nxf[1];
    const float gg0 = nxg[0], gg1 = nxg[1], go0 = nxo[0], go1 = nxo[1];
    if (s < 255){
      const int s2 = s + 1, t2 = s2 & 127;
      const float* G2 = (s2 >> 7) ? GinD : GinE;
      const float* gp = G2 + (size_t)((t2 << 5) + b_own) * 2048 + j_own;
      nxi = *(const f32x2*)(gp);        nxf = *(const f32x2*)(gp + 512);
      nxg = *(const f32x2*)(gp + 1024); nxo = *(const f32x2*)(gp + 1536);
    }
    // ---- MFMA: A from poll regs (mask tags), B from weight LDS; 4 independent chains ----
    f32x4 a0 = {0.f, 0.f, 0.f, 0.f}, a0b = {0.f, 0.f, 0.f, 0.f};
    f32x4 a1 = {0.f, 0.f, 0.f, 0.f}, a1b = {0.f, 0.f, 0.f, 0.f};
    #pragma unroll
    for (int ks = 0; ks < 16; ++ks){
      union { uint4 u; s16x8 v; } ua;
      ua.u.x = vv[ks].x & 0xFFFEFFFEu;
      ua.u.y = vv[ks].y & 0xFFFEFFFEu;
      ua.u.z = vv[ks].z & 0xFFFEFFFEu;
      ua.u.w = vv[ks].w & 0xFFFEFFFEu;
      const int ko = ((ks << 6) + (lg << 4)) ^ swz;
      const s16x8 b0 = *(const s16x8*)(wrow0 + ko);
      const s16x8 b1 = *(const s16x8*)(wrow1 + ko);
      if (ks & 1){
        a0b = __builtin_amdgcn_mfma_f32_16x16x32_bf16(ua.v, b0, a0b, 0, 0, 0);
        a1b = __builtin_amdgcn_mfma_f32_16x16x32_bf16(ua.v, b1, a1b, 0, 0, 0);
      } else {
        a0 = __builtin_amdgcn_mfma_f32_16x16x32_bf16(ua.v, b0, a0, 0, 0, 0);
        a1 = __builtin_amdgcn_mfma_f32_16x16x32_bf16(ua.v, b1, a1, 0, 0, 0);
      }
    }
    a0 += a0b; a1 += a1b;
    // ---- intra-wave transpose: lane -> its 2 units x 4 gates ----
    float vi0 = 0.f, vi1 = 0.f, vf0 = 0.f, vf1 = 0.f, vg0 = 0.f, vg1 = 0.f, vo0 = 0.f, vo1 = 0.f;
    #pragma unroll
    for (int r = 0; r < 4; ++r){
      const int ti0 = __builtin_amdgcn_ds_bpermute(ad_l0, __float_as_int(a0[r]));
      const int ti1 = __builtin_amdgcn_ds_bpermute(ad_l1, __float_as_int(a0[r]));
      const int tf0 = __builtin_amdgcn_ds_bpermute(ad_h0, __float_as_int(a0[r]));
      const int tf1 = __builtin_amdgcn_ds_bpermute(ad_h1, __float_as_int(a0[r]));
      const int tg0 = __builtin_amdgcn_ds_bpermute(ad_l0, __float_as_int(a1[r]));
      const int tg1 = __builtin_amdgcn_ds_bpermute(ad_l1, __float_as_int(a1[r]));
      const int to0 = __builtin_amdgcn_ds_bpermute(ad_h0, __float_as_int(a1[r]));
      const int to1 = __builtin_amdgcn_ds_bpermute(ad_h1, __float_as_int(a1[r]));
      if (myr == r){
        vi0 = __int_as_float(ti0); vi1 = __int_as_float(ti1);
        vf0 = __int_as_float(tf0); vf1 = __int_as_float(tf1);
        vg0 = __int_as_float(tg0); vg1 = __int_as_float(tg1);
        vo0 = __int_as_float(to0); vo1 = __int_as_float(to1);
      }
    }
    // ---- combine 2 units, publish tagged u32 (the single cross-block event) ----
    const uint tgn = (uint)(((s + 1) >> 1) & 1);
    float h0f, h1f;
    { const float si = sigm(vi0 + gi0), sf = sigm(vf0 + gf0), so = sigm(vo0 + go0);
      cc0 = sf * cc0 + si * fast_tanh(vg0 + gg0); h0f = so * fast_tanh(cc0); }
    { const float si = sigm(vi1 + gi1), sf = sigm(vf1 + gf1), so = sigm(vo1 + go1);
      cc1 = sf * cc1 + si * fast_tanh(vg1 + gg1); h1f = so * fast_tanh(cc1); }
    const uint hb0 = (uint)f2bf(h0f), hb1 = (uint)f2bf(h1f);
    const uint hclean = (hb1 << 16) | hb0;
    const uint htag = (((hb1 & 0xFFFEu) | tgn) << 16) | ((hb0 & 0xFFFEu) | tgn);
    __hip_atomic_store((uint*)hbuf + (((s + 1) & 1) << 13) + (m << 12) + (bk << 8) + (jt << 6) + (beta << 2) + p,
                       htag, __ATOMIC_RELAXED, __HIP_MEMORY_SCOPE_AGENT);
    // off-critical-path clean stores
    uint* hall = (uint*)(ph ? decO : encO);
    hall[((size_t)((t << 5) + b_own) << 8) + (j_own >> 1)] = hclean;
    if (ph) ((uint*)Ac)[((size_t)((t << 5) + b_own) << 9) + 256 + (j_own >> 1)] = hclean;
  }
}

// ---------------- fused attention: scores -> softmax -> ctx, per (b, s-tile of 16) ----------------
__global__ __launch_bounds__(256) void k_attn(const ushort* __restrict__ enc, const ushort* __restrict__ dec,
                                              ushort* __restrict__ Ac){
  __shared__ __align__(16) float dec_lds[16 * 512];
  __shared__ __align__(16) float P[16 * 128];
  const int tid = threadIdx.x;
  const int b = blockIdx.x & 31, st = blockIdx.x >> 5;
  const int s0 = st << 4;
  for (int j = 0; j < 4; ++j){
    int e8 = tid + (j << 8);
    int sl = e8 >> 6, k = (e8 & 63) << 3;
    uint4 v = *(const uint4*)(dec + ((size_t)((s0 + sl) * 32 + b) << 9) + k);
    float* dst = dec_lds + sl * 512 + k;
    dst[0] = bfl(v.x); dst[1] = bfh(v.x); dst[2] = bfl(v.y); dst[3] = bfh(v.y);
    dst[4] = bfl(v.z); dst[5] = bfh(v.z); dst[6] = bfl(v.w); dst[7] = bfh(v.w);
  }
  __syncthreads();
  {
    const int tl = tid & 127, sh = tid >> 7;
    const ushort* erow = enc + ((size_t)(tl * 32 + b) << 9);
    float acc8[8] = {0.f, 0.f, 0.f, 0.f, 0.f, 0.f, 0.f, 0.f};
    for (int k = 0; k < 512; k += 8){
      uint4 v = *(const uint4*)(erow + k);
      const float e0 = bfl(v.x), e1 = bfh(v.x), e2 = bfl(v.y), e3 = bfh(v.y);
      const float e4 = bfl(v.z), e5 = bfh(v.z), e6 = bfl(v.w), e7 = bfh(v.w);
      const float* dl = dec_lds + (sh << 3) * 512 + k;
      #pragma unroll
      for (int i = 0; i < 8; ++i){
        f32x4 d0 = *(const f32x4*)(dl + i * 512);
        f32x4 d1 = *(const f32x4*)(dl + i * 512 + 4);
        acc8[i] += d0[0]*e0 + d0[1]*e1 + d0[2]*e2 + d0[3]*e3
                 + d1[0]*e4 + d1[1]*e5 + d1[2]*e6 + d1[3]*e7;
      }
    }
    #pragma unroll
    for (int i = 0; i < 8; ++i) P[((sh << 3) + i) * 128 + tl] = acc8[i];
  }
  __syncthreads();
  {
    const int r = tid >> 4, i = tid & 15;
    float* prow = P + r * 128 + (i << 3);
    float v[8], mx = -1e30f;
    #pragma unroll
    for (int j = 0; j < 8; ++j){ v[j] = prow[j]; mx = fmaxf(mx, v[j]); }
    #pragma unroll
    for (int off = 1; off < 16; off <<= 1) mx = fmaxf(mx, __shfl_xor(mx, off));
    float l = 0.f;
    #pragma unroll
    for (int j = 0; j < 8; ++j){ v[j] = __expf(v[j] - mx); l += v[j]; }
    #pragma unroll
    for (int off = 1; off < 16; off <<= 1) l += __shfl_xor(l, off);
    const float inv = 1.f / l;
    #pragma unroll
    for (int j = 0; j < 8; ++j) prow[j] = v[j] * inv;
  }
  __syncthreads();
  {
    const int h0 = tid << 1;
    float acc[16][2];
    #pragma unroll
    for (int sl = 0; sl < 16; ++sl){ acc[sl][0] = 0.f; acc[sl][1] = 0.f; }
    const ushort* ecol = enc + ((size_t)b << 9) + h0;
    for (int t = 0; t < 128; ++t){
      uint v = *(const uint*)(ecol + (size_t)t * 16384);
      const float e0 = bfl(v), e1 = bfh(v);
      #pragma unroll
      for (int sl = 0; sl < 16; ++sl){
        const float p = P[sl * 128 + t];
        acc[sl][0] += p * e0; acc[sl][1] += p * e1;
      }
    }
    #pragma unroll
    for (int sl = 0; sl < 16; ++sl){
      const int mm = (s0 + sl) * 32 + b;
      uint u = ((uint)f2bf(acc[sl][1]) << 16) | (uint)f2bf(acc[sl][0]);
      *(uint*)(Ac + (size_t)mm * 1024 + h0) = u;
    }
  }
}

// ---------------- fused: reduce per-tile (m,l) partials -> lse, subtract in place ----------------
__global__ __launch_bounds__(256) void k_sub(float* __restrict__ out,
                                             const float* __restrict__ pM, const float* __restrict__ pL){
  __shared__ float slse;
  const int row = blockIdx.x;
  const int tid = threadIdx.x;
  if (tid < 64){
    float m = -1e30f, l = 0.f;
    for (int i = tid; i < 250; i += 64){
      float m2 = pM[(size_t)row * 256 + i], l2 = pL[(size_t)row * 256 + i];
      float nm = fmaxf(m, m2);
      l = l * __expf(m - nm) + l2 * __expf(m2 - nm);
      m = nm;
    }
    #pragma unroll
    for (int off = 32; off; off >>= 1){
      float m2 = __shfl_xor(m, off), l2 = __shfl_xor(l, off);
      float nm = fmaxf(m, m2);
      l = l * __expf(m - nm) + l2 * __expf(m2 - nm);
      m = nm;
    }
    if (tid == 0) slse = m + __logf(l);
  }
  __syncthreads();
  const float s = slse;
  float* p = out + (size_t)row * VD;
  for (int i4 = tid; i4 < VD / 4; i4 += 256){
    f32x4 v = *(const f32x4*)(p + ((size_t)i4 << 2));
    v[0] -= s; v[1] -= s; v[2] -= s; v[3] -= s;
    *(f32x4*)(p + ((size_t)i4 << 2)) = v;
  }
}

extern "C" void kernel_launch(void* const* d_in, const int* in_sizes, int n_in,
                              void* d_out, int out_size, void* d_ws, size_t ws_size,
                              hipStream_t stream){
  const int*   enc_in  = (const int*)d_in[0];
  const int*   dec_in  = (const int*)d_in[1];
  const float* enc_emb = (const float*)d_in[2];
  const float* dec_emb = (const float*)d_in[3];
  const float* WihE    = (const float*)d_in[4];
  const float* WhhE    = (const float*)d_in[5];
  const float* WihD    = (const float*)d_in[6];
  const float* WhhD    = (const float*)d_in[7];
  const float* We      = (const float*)d_in[8];
  const float* be      = (const float*)d_in[9];
  const float* Wd      = (const float*)d_in[10];
  const float* bd      = (const float*)d_in[11];
  const float* outW    = (const float*)d_in[12];
  const float* outb    = (const float*)d_in[13];
  float* out = (float*)d_out;

  char* ws = (char*)d_ws;
  size_t off = 0;
  auto alloc = [&](size_t bytes){ void* p = ws + off; off += (bytes + 255) & ~(size_t)255; return p; };
  ushort* xe    = (ushort*)alloc((size_t)MM * HH * 2);
  ushort* xd    = (ushort*)alloc((size_t)MM * HH * 2);
  ushort* WihEb = (ushort*)alloc((size_t)2048 * 512 * 2);
  ushort* WihDb = (ushort*)alloc((size_t)2048 * 512 * 2);
  ushort* Bc    = (ushort*)alloc((size_t)512 * 1024 * 2);
  float*  bsum  = (float*)alloc(512 * 4);
  ushort* outWb = (ushort*)alloc((size_t)VD * HH * 2);
  ushort* encO  = (ushort*)alloc((size_t)MM * HH * 2);
  ushort* decO  = (ushort*)alloc((size_t)MM * HH * 2);
  u64*    hbuf  = (u64*)alloc(8192 * 8);               // 64 KB tagged-bf16 double buffer
  ushort* Ac    = (ushort*)alloc((size_t)MM * 1024 * 2);
  ushort* hid   = (ushort*)alloc((size_t)MM * HH * 2);
  float*  pbufM = (float*)alloc((size_t)MM * 256 * 4); // 4 MB
  float*  pbufL = (float*)alloc((size_t)MM * 256 * 4); // 4 MB
  // Gin buffers (67 MB) live in d_out-as-scratch: dead before logits GEMM writes d_out.
  float* GinE = out;
  float* GinD = out + (size_t)MM * 2048;

  k_init<<<dim3(32), dim3(256), 0, stream>>>(hbuf);
  k_cvt<<<dim3(1024), dim3(256), 0, stream>>>(WihE, WihEb, 2048 * 512 / 4);
  k_cvt<<<dim3(1024), dim3(256), 0, stream>>>(WihD, WihDb, 2048 * 512 / 4);
  k_cvt<<<dim3(2048), dim3(256), 0, stream>>>(outW, outWb, VD * HH / 4);
  k_concatB<<<dim3(512), dim3(128), 0, stream>>>(We, Wd, Bc);
  k_bsum<<<dim3(2), dim3(256), 0, stream>>>(be, bd, bsum);
  k_embed<<<dim3(MM), dim3(128), 0, stream>>>(enc_in, enc_emb, xe);
  k_embed<<<dim3(MM), dim3(128), 0, stream>>>(dec_in, dec_emb, xd);
  // input projections: Gin = x @ Wih^T   [4096,512]x[2048,512]^T
  k_gemm<false, false, false, false><<<dim3(16, 32), dim3(256), 0, stream>>>(xe, WihEb, (const float*)nullptr, GinE, MM, 2048, 512, nullptr, nullptr);
  k_gemm<false, false, false, false><<<dim3(16, 32), dim3(256), 0, stream>>>(xd, WihDb, (const float*)nullptr, GinD, MM, 2048, 512, nullptr, nullptr);
  // both LSTMs (persistent, barrier-free self-polling waves)
  k_lstm<<<dim3(NLB), dim3(512), 0, stream>>>(GinE, GinD, WhhE, WhhD, hbuf, encO, decO, Ac);
  // attention -> ctx into Ac[:, 0:512] (dec h already in Ac[:, 512:1024])
  k_attn<<<dim3(256), dim3(256), 0, stream>>>(encO, decO, Ac);
  // hidden = tanh([ctx|dec] @ [We|Wd]^T + (be+bd))   K=1024 -> bf16
  k_gemm<true, true, true, false><<<dim3(4, 32), dim3(256), 0, stream>>>(Ac, Bc, bsum, hid, MM, 512, 1024, nullptr, nullptr);
  // logits = hidden @ outW^T + out_b -> d_out (f32), + per-tile lse partials
  k_gemm<true, false, false, true><<<dim3(250, 32), dim3(256), 0, stream>>>(hid, outWb, outb, out, MM, VD, 512, pbufM, pbufL);
  // log-softmax: fused lse-reduce + subtract
  k_sub<<<dim3(MM), dim3(256), 0, stream>>>(out, pbufM, pbufL);
}

// Round 10
// 1642.533 us; speedup vs baseline: 1.2043x; 1.2043x over previous
//
#include <hip/hip_runtime.h>
#include <stdint.h>

#define TT 128
#define BB 32
#define HH 512
#define MM 4096            // T*B == S*B
#define VD 32000
#define NLB 16             // persistent LSTM blocks (one j-slice of 32 h-units each)

typedef float f32x4 __attribute__((ext_vector_type(4)));
typedef short s16x8 __attribute__((ext_vector_type(8)));
typedef unsigned long long u64;

#define TAGMASK 0x0001000100010001ull

__device__ __forceinline__ ushort f2bf(float f){
  uint u = __float_as_uint(f);
  return (ushort)((u + 0x7fffu + ((u >> 16) & 1u)) >> 16);   // RTNE
}
__device__ __forceinline__ float bfl(uint v){ return __uint_as_float(v << 16); }
__device__ __forceinline__ float bfh(uint v){ return __uint_as_float(v & 0xffff0000u); }
__device__ __forceinline__ float bfu(ushort v){ return __uint_as_float(((uint)v) << 16); }
__device__ __forceinline__ float fast_tanh(float x){
  return 1.f - 2.f / (1.f + __expf(2.f * x));   // exact at saturation, ~1e-6 mid-range
}

// ---------------- init: h double buffer. parity0 = h(0)=0 tag0 (valid); parity1 = tag1 (stale) ----
__global__ void k_init(u64* hbuf){
  int i = blockIdx.x * 256 + threadIdx.x;
  if (i < 4096) hbuf[i] = 0ull;
  else if (i < 8192) hbuf[i] = TAGMASK;   // tag=1: consumers at s=0/1 (tag0) won't accept
}

// ---------------- f32 -> bf16 convert ----------------
__global__ __launch_bounds__(256) void k_cvt(const float* __restrict__ s, ushort* __restrict__ d, int n4){
  int i = blockIdx.x * 256 + threadIdx.x;
  int st = gridDim.x * 256;
  for (; i < n4; i += st){
    f32x4 v = *(const f32x4*)(s + (size_t)i * 4);
    ushort4 o; o.x = f2bf(v[0]); o.y = f2bf(v[1]); o.z = f2bf(v[2]); o.w = f2bf(v[3]);
    *(ushort4*)(d + (size_t)i * 4) = o;
  }
}

// ---------------- embedding gather -> bf16 ----------------
__global__ __launch_bounds__(128) void k_embed(const int* __restrict__ ids, const float* __restrict__ emb,
                                               ushort* __restrict__ out){
  int row = blockIdx.x, t = threadIdx.x;     // 4096 rows, 128 thr
  int id = ids[row];
  f32x4 v = *(const f32x4*)(emb + (size_t)id * HH + t * 4);
  ushort4 o; o.x = f2bf(v[0]); o.y = f2bf(v[1]); o.z = f2bf(v[2]); o.w = f2bf(v[3]);
  *(ushort4*)(out + (size_t)row * HH + t * 4) = o;
}

// ---------------- build concat weight [512][1024] = [We | Wd] ----------------
__global__ __launch_bounds__(128) void k_concatB(const float* __restrict__ We, const float* __restrict__ Wd,
                                                 ushort* __restrict__ Bc){
  int n = blockIdx.x, t = threadIdx.x;       // 512 rows, 128 thr
  f32x4 a = *(const f32x4*)(We + (size_t)n * HH + t * 4);
  f32x4 b = *(const f32x4*)(Wd + (size_t)n * HH + t * 4);
  ushort4 oa, ob;
  oa.x = f2bf(a[0]); oa.y = f2bf(a[1]); oa.z = f2bf(a[2]); oa.w = f2bf(a[3]);
  ob.x = f2bf(b[0]); ob.y = f2bf(b[1]); ob.z = f2bf(b[2]); ob.w = f2bf(b[3]);
  *(ushort4*)(Bc + (size_t)n * 1024 + t * 4) = oa;
  *(ushort4*)(Bc + (size_t)n * 1024 + 512 + t * 4) = ob;
}
__global__ void k_bsum(const float* a, const float* b, float* o){
  int i = blockIdx.x * 256 + threadIdx.x;
  if (i < HH) o[i] = a[i] + b[i];
}

// ---------------- bf16 MFMA GEMM, C = A[M,K] * B[N,K]^T (+bias)(+tanh)(+lse partials) ----------------
// ldc = output leading dimension in elements (allows writing into strided row slots).
template<bool BIAS, bool TANH, bool OUTBF, bool LSE>
__global__ __launch_bounds__(256) void k_gemm(const ushort* __restrict__ A, const ushort* __restrict__ Bm,
                                              const float* __restrict__ bias, void* __restrict__ Cout,
                                              int Mtot, int Ntot, int K, int ldc,
                                              float* __restrict__ pbufM, float* __restrict__ pbufL){
  __shared__ __align__(16) ushort As[128 * 32];
  __shared__ __align__(16) ushort Bs[128 * 32];
  __shared__ float sMm[2][128], sMl[2][128];
  const int tid = threadIdx.x;
  const int m0 = blockIdx.y << 7, n0 = blockIdx.x << 7;
  const int wid = tid >> 6, lane = tid & 63;
  const int wm = wid >> 1, wn = wid & 1;
  const int lr = lane & 15, lg = lane >> 4;
  const int lk = lg << 3, cr = lg << 2;
  f32x4 acc[4][4];
  for (int i = 0; i < 4; ++i)
    for (int j = 0; j < 4; ++j)
      acc[i][j] = (f32x4){0.f, 0.f, 0.f, 0.f};
  const int c0 = tid, c1 = tid + 256;
  const size_t ar0 = (size_t)(m0 + (c0 >> 2)) * K + ((c0 & 3) << 3);
  const size_t ar1 = (size_t)(m0 + (c1 >> 2)) * K + ((c1 & 3) << 3);
  const size_t br0 = (size_t)(n0 + (c0 >> 2)) * K + ((c0 & 3) << 3);
  const size_t br1 = (size_t)(n0 + (c1 >> 2)) * K + ((c1 & 3) << 3);
  for (int k0 = 0; k0 < K; k0 += 32){
    __syncthreads();
    __builtin_amdgcn_global_load_lds((const __attribute__((address_space(1))) void*)(A + ar0 + k0),
                                     (__attribute__((address_space(3))) void*)(As + (c0 << 3)), 16, 0, 0);
    __builtin_amdgcn_global_load_lds((const __attribute__((address_space(1))) void*)(A + ar1 + k0),
                                     (__attribute__((address_space(3))) void*)(As + (c1 << 3)), 16, 0, 0);
    __builtin_amdgcn_global_load_lds((const __attribute__((address_space(1))) void*)(Bm + br0 + k0),
                                     (__attribute__((address_space(3))) void*)(Bs + (c0 << 3)), 16, 0, 0);
    __builtin_amdgcn_global_load_lds((const __attribute__((address_space(1))) void*)(Bm + br1 + k0),
                                     (__attribute__((address_space(3))) void*)(Bs + (c1 << 3)), 16, 0, 0);
    __syncthreads();
    s16x8 af[4], bf[4];
    #pragma unroll
    for (int f = 0; f < 4; ++f){
      af[f] = *(const s16x8*)(As + ((wm << 6) + (f << 4) + lr) * 32 + lk);
      bf[f] = *(const s16x8*)(Bs + ((wn << 6) + (f << 4) + lr) * 32 + lk);
    }
    #pragma unroll
    for (int fm = 0; fm < 4; ++fm)
      #pragma unroll
      for (int fn = 0; fn < 4; ++fn)
        acc[fm][fn] = __builtin_amdgcn_mfma_f32_16x16x32_bf16(af[fm], bf[fn], acc[fm][fn], 0, 0, 0);
  }
  float bv4[4];
  #pragma unroll
  for (int fn = 0; fn < 4; ++fn)
    bv4[fn] = BIAS ? bias[n0 + (wn << 6) + (fn << 4) + lr] : 0.f;
  float mv[16], lv[16];
  #pragma unroll
  for (int fm = 0; fm < 4; ++fm){
    #pragma unroll
    for (int r = 0; r < 4; ++r){
      const int rw = m0 + (wm << 6) + (fm << 4) + cr + r;
      float vs[4], vmax = -1e30f;
      #pragma unroll
      for (int fn = 0; fn < 4; ++fn){
        float v = acc[fm][fn][r] + bv4[fn];
        if (TANH) v = tanhf(v);
        vs[fn] = v;
        if (LSE) vmax = fmaxf(vmax, v);
        const size_t off = (size_t)rw * ldc + (n0 + (wn << 6) + (fn << 4) + lr);
        if (OUTBF) ((ushort*)Cout)[off] = f2bf(v);
        else       ((float*)Cout)[off] = v;
      }
      if (LSE){
        float l4 = 0.f;
        #pragma unroll
        for (int fn = 0; fn < 4; ++fn) l4 += __expf(vs[fn] - vmax);
        mv[(fm << 2) + r] = vmax; lv[(fm << 2) + r] = l4;
      }
    }
  }
  if (LSE){
    #pragma unroll
    for (int q = 0; q < 16; ++q){
      #pragma unroll
      for (int off = 1; off < 16; off <<= 1){
        float m2 = __shfl_xor(mv[q], off), l2 = __shfl_xor(lv[q], off);
        float nm = fmaxf(mv[q], m2);
        lv[q] = lv[q] * __expf(mv[q] - nm) + l2 * __expf(m2 - nm);
        mv[q] = nm;
      }
    }
    float selM = -1e30f, selL = 0.f;
    #pragma unroll
    for (int q = 0; q < 16; ++q){
      selM = (lr == q) ? mv[q] : selM;
      selL = (lr == q) ? lv[q] : selL;
    }
    const int lrow = (wm << 6) + ((lr >> 2) << 4) + (lg << 2) + (lr & 3);
    sMm[wn][lrow] = selM; sMl[wn][lrow] = selL;
    __syncthreads();
    if (tid < 128){
      float ma = sMm[0][tid], mb = sMm[1][tid];
      float nm = fmaxf(ma, mb);
      float l = sMl[0][tid] * __expf(ma - nm) + sMl[1][tid] * __expf(mb - nm);
      pbufM[(size_t)(m0 + tid) * 256 + blockIdx.x] = nm;
      pbufL[(size_t)(m0 + tid) * 256 + blockIdx.x] = l;
    }
  }
}

// ---------------- persistent LSTM: 16 blocks x 512 thr, MFMA recurrence (r7 version, 1028 us) ----
// Exchange v6: tag-in-bf16-LSB + A-fragment-ordered hbuf for coalesced polling.
// hbuf u64 layout: [parity][m 2][ks 16][lg 4][b 16][half 2]; a wave's poll load for one ks
// is 64 lanes x 16B CONTIGUOUS (1 KB) -> 16 asm global_load_dwordx4 sc0 sc1 per round.
// Block bk owns j in [bk*32, bk*32+32) == ks group bk exactly; its stores hit block-private
// lines. Weights (4g x 32j x 512k bf16 = 128 KB) staged in LDS, XOR-swizzled. Wave (m,g)
// computes 2 j-tiles x 16 ks MFMAs. Combine = 256 threads (b, q): 4 j-units each, one u64
// tagged agent store = the single cross-block visibility event. One barrier per step.
__global__ __launch_bounds__(512) void k_lstm(const float* __restrict__ GinE, const float* __restrict__ GinD,
                                              const float* __restrict__ WhhE, const float* __restrict__ WhhD,
                                              u64* __restrict__ hbuf,
                                              ushort* __restrict__ encO, ushort* __restrict__ decO,
                                              ushort* __restrict__ Ac){
  __shared__ __align__(16) ushort wlds[4 * 32 * 512];  // 128 KB
  __shared__ __align__(16) float gbuf[128 * 36];       // rows (g*32+b), +pad, 18.4 KB
  const int tid = threadIdx.x;
  const int bk = blockIdx.x;
  const int J0 = bk << 5;
  const int w = tid >> 6, lane = tid & 63;
  const int m = w & 1, g = w >> 1;
  const int lr = lane & 15, lg = lane >> 4;
  const int cb = tid >> 3, cq = tid & 7;    // combine mapping (tid<256): batch, j-quad-group

  f32x4 c4 = {0.f, 0.f, 0.f, 0.f};          // 4 cell states per combine thread
  f32x4 gin4[4];

  if (tid < 256){                           // prologue: Gin for s=0
    const float* gp = GinE + (size_t)cb * 2048 + J0 + (cq << 2);
    gin4[0] = *(const f32x4*)(gp);
    gin4[1] = *(const f32x4*)(gp + 512);
    gin4[2] = *(const f32x4*)(gp + 1024);
    gin4[3] = *(const f32x4*)(gp + 1536);
  }

  const char* wr0 = (const char*)wlds + (g << 15) + (lr << 10);  // B row jl=lr (tile 0)
  const int swz = (lr & 7) << 4;

  for (int s = 0; s < 256; ++s){
    const int ph = s >> 7, t = s & 127;
    if (t == 0){
      // ---- stage Whh -> LDS (bf16, XOR-swizzled). thread = (row 0..127, k-quarter) ----
      const float* Whh = ph ? WhhD : WhhE;
      const int rr = tid >> 2, kq = tid & 3;
      const int gg = rr >> 5, jl = rr & 31;
      const float* src = Whh + (size_t)((gg << 9) + J0 + jl) * 512 + (kq << 7);
      char* dstrow = (char*)wlds + (size_t)(((gg << 5) + jl) << 10);
      #pragma unroll
      for (int i = 0; i < 16; ++i){
        f32x4 wa = *(const f32x4*)(src + (i << 3));
        f32x4 wc = *(const f32x4*)(src + (i << 3) + 4);
        uint4 pk;
        pk.x = ((uint)f2bf(wa[1]) << 16) | f2bf(wa[0]);
        pk.y = ((uint)f2bf(wa[3]) << 16) | f2bf(wa[2]);
        pk.z = ((uint)f2bf(wc[1]) << 16) | f2bf(wc[0]);
        pk.w = ((uint)f2bf(wc[3]) << 16) | f2bf(wc[2]);
        *(uint4*)(dstrow + ((((kq << 4) + i) << 4) ^ ((jl & 7) << 4))) = pk;
      }
      __syncthreads();                      // weights ready
    }
    // ---- coalesced poll-load h(s): 16 x dwordx4 (sc0 sc1 = cache-bypassing) ----
    const uint pat = ((s >> 1) & 1) ? 0x00010001u : 0u;
    const char* hp = (const char*)hbuf + ((s & 1) << 15) + (m << 14) + (lg << 8) + (lr << 4);
    uint4 vv[16];
    for (;;){
      #pragma unroll
      for (int ks = 0; ks < 16; ++ks)
        asm volatile("global_load_dwordx4 %0, %1, off sc0 sc1"
                     : "=v"(vv[ks]) : "v"(hp + (ks << 10)) : "memory");
      asm volatile("s_waitcnt vmcnt(0)" ::: "memory");
      __builtin_amdgcn_sched_barrier(0);
      uint bad = 0u;
      #pragma unroll
      for (int ks = 0; ks < 16; ++ks)
        bad |= (vv[ks].x ^ pat) | (vv[ks].y ^ pat) | (vv[ks].z ^ pat) | (vv[ks].w ^ pat);
      if (__all((bad & 0x00010001u) == 0u)) break;
    }
    // ---- MFMA: A = h frags (mask tag LSBs), B = weight frags (LDS), 2 j-tiles ----
    f32x4 a0 = {0.f, 0.f, 0.f, 0.f}, a1 = {0.f, 0.f, 0.f, 0.f};
    #pragma unroll
    for (int ks = 0; ks < 16; ++ks){
      union { uint4 u; s16x8 v; } ua;
      ua.u.x = vv[ks].x & 0xFFFEFFFEu;
      ua.u.y = vv[ks].y & 0xFFFEFFFEu;
      ua.u.z = vv[ks].z & 0xFFFEFFFEu;
      ua.u.w = vv[ks].w & 0xFFFEFFFEu;
      const int ko = ((ks << 6) + (lg << 4)) ^ swz;
      const s16x8 b0 = *(const s16x8*)(wr0 + ko);
      const s16x8 b1 = *(const s16x8*)(wr0 + (16 << 10) + ko);
      a0 = __builtin_amdgcn_mfma_f32_16x16x32_bf16(ua.v, b0, a0, 0, 0, 0);
      a1 = __builtin_amdgcn_mfma_f32_16x16x32_bf16(ua.v, b1, a1, 0, 0, 0);
    }
    // D-frags: row = g*32 + (m*16 + lg*4 + r), cols jl = lr / 16+lr
    #pragma unroll
    for (int r = 0; r < 4; ++r){
      const int row = (g << 5) + (m << 4) + (lg << 2) + r;
      gbuf[row * 36 + lr] = a0[r];
      gbuf[row * 36 + 16 + lr] = a1[r];
    }
    __syncthreads();                        // gbuf ready (the ONE barrier per step)
    if (tid < 256){
      // ---- gate combine + state update: thread (cb, cq), 4 units (j = 4cq..4cq+4) ----
      f32x4 z0 = *(const f32x4*)(gbuf + (      cb) * 36 + (cq << 2));
      f32x4 z1 = *(const f32x4*)(gbuf + (32 + cb) * 36 + (cq << 2));
      f32x4 z2 = *(const f32x4*)(gbuf + (64 + cb) * 36 + (cq << 2));
      f32x4 z3 = *(const f32x4*)(gbuf + (96 + cb) * 36 + (cq << 2));
      z0 += gin4[0]; z1 += gin4[1]; z2 += gin4[2]; z3 += gin4[3];
      const uint tgn = (uint)(((s + 1) >> 1) & 1);
      u64 htag = 0ull, hclean = 0ull;
      #pragma unroll
      for (int e = 0; e < 4; ++e){
        const float si = 1.f / (1.f + __expf(-z0[e]));
        const float sf = 1.f / (1.f + __expf(-z1[e]));
        const float so = 1.f / (1.f + __expf(-z3[e]));
        const float cc = sf * c4[e] + si * fast_tanh(z2[e]);
        c4[e] = cc;
        const uint hb = (uint)f2bf(so * fast_tanh(cc));
        hclean |= (u64)hb << (e << 4);
        htag   |= (u64)((hb & 0xFFFEu) | tgn) << (e << 4);
      }
      // the single critical-path event: one plain agent store (ks = bk region, private lines)
      __hip_atomic_store(hbuf + (((size_t)((s + 1) & 1)) << 12) + ((cb >> 4) << 11) + (bk << 7)
                              + ((cq >> 1) << 5) + ((cb & 15) << 1) + (cq & 1), htag,
                         __ATOMIC_RELAXED, __HIP_MEMORY_SCOPE_AGENT);
      // off-critical-path stores (clean h)
      u64* hallq = (u64*)(ph ? decO : encO);
      __hip_atomic_store(hallq + (size_t)(t * 32 + cb) * 128 + (bk << 3) + cq, hclean,
                         __ATOMIC_RELAXED, __HIP_MEMORY_SCOPE_AGENT);
      if (ph)
        __hip_atomic_store((u64*)Ac + (size_t)(t * 32 + cb) * 256 + 128 + (bk << 3) + cq, hclean,
                           __ATOMIC_RELAXED, __HIP_MEMORY_SCOPE_AGENT);
      if (s < 255){                         // prefetch Gin(s+1)
        const int s2 = s + 1, t2 = s2 & 127;
        const float* G2 = (s2 >> 7) ? GinD : GinE;
        const float* gp = G2 + (size_t)(t2 * 32 + cb) * 2048 + J0 + (cq << 2);
        gin4[0] = *(const f32x4*)(gp);
        gin4[1] = *(const f32x4*)(gp + 512);
        gin4[2] = *(const f32x4*)(gp + 1024);
        gin4[3] = *(const f32x4*)(gp + 1536);
      }
    }
  }
}

// ---------------- fused attention: scores -> softmax -> ctx, per (b, s-tile of 16) ----------------
__global__ __launch_bounds__(256) void k_attn(const ushort* __restrict__ enc, const ushort* __restrict__ dec,
                                              ushort* __restrict__ Ac){
  __shared__ __align__(16) float dec_lds[16 * 512];
  __shared__ __align__(16) float P[16 * 128];
  const int tid = threadIdx.x;
  const int b = blockIdx.x & 31, st = blockIdx.x >> 5;
  const int s0 = st << 4;
  for (int j = 0; j < 4; ++j){
    int e8 = tid + (j << 8);
    int sl = e8 >> 6, k = (e8 & 63) << 3;
    uint4 v = *(const uint4*)(dec + ((size_t)((s0 + sl) * 32 + b) << 9) + k);
    float* dst = dec_lds + sl * 512 + k;
    dst[0] = bfl(v.x); dst[1] = bfh(v.x); dst[2] = bfl(v.y); dst[3] = bfh(v.y);
    dst[4] = bfl(v.z); dst[5] = bfh(v.z); dst[6] = bfl(v.w); dst[7] = bfh(v.w);
  }
  __syncthreads();
  {
    const int tl = tid & 127, sh = tid >> 7;
    const ushort* erow = enc + ((size_t)(tl * 32 + b) << 9);
    float acc8[8] = {0.f, 0.f, 0.f, 0.f, 0.f, 0.f, 0.f, 0.f};
    for (int k = 0; k < 512; k += 8){
      uint4 v = *(const uint4*)(erow + k);
      const float e0 = bfl(v.x), e1 = bfh(v.x), e2 = bfl(v.y), e3 = bfh(v.y);
      const float e4 = bfl(v.z), e5 = bfh(v.z), e6 = bfl(v.w), e7 = bfh(v.w);
      const float* dl = dec_lds + (sh << 3) * 512 + k;
      #pragma unroll
      for (int i = 0; i < 8; ++i){
        f32x4 d0 = *(const f32x4*)(dl + i * 512);
        f32x4 d1 = *(const f32x4*)(dl + i * 512 + 4);
        acc8[i] += d0[0]*e0 + d0[1]*e1 + d0[2]*e2 + d0[3]*e3
                 + d1[0]*e4 + d1[1]*e5 + d1[2]*e6 + d1[3]*e7;
      }
    }
    #pragma unroll
    for (int i = 0; i < 8; ++i) P[((sh << 3) + i) * 128 + tl] = acc8[i];
  }
  __syncthreads();
  {
    const int r = tid >> 4, i = tid & 15;
    float* prow = P + r * 128 + (i << 3);
    float v[8], mx = -1e30f;
    #pragma unroll
    for (int j = 0; j < 8; ++j){ v[j] = prow[j]; mx = fmaxf(mx, v[j]); }
    #pragma unroll
    for (int off = 1; off < 16; off <<= 1) mx = fmaxf(mx, __shfl_xor(mx, off));
    float l = 0.f;
    #pragma unroll
    for (int j = 0; j < 8; ++j){ v[j] = __expf(v[j] - mx); l += v[j]; }
    #pragma unroll
    for (int off = 1; off < 16; off <<= 1) l += __shfl_xor(l, off);
    const float inv = 1.f / l;
    #pragma unroll
    for (int j = 0; j < 8; ++j) prow[j] = v[j] * inv;
  }
  __syncthreads();
  {
    const int h0 = tid << 1;
    float acc[16][2];
    #pragma unroll
    for (int sl = 0; sl < 16; ++sl){ acc[sl][0] = 0.f; acc[sl][1] = 0.f; }
    const ushort* ecol = enc + ((size_t)b << 9) + h0;
    for (int t = 0; t < 128; ++t){
      uint v = *(const uint*)(ecol + (size_t)t * 16384);
      const float e0 = bfl(v), e1 = bfh(v);
      #pragma unroll
      for (int sl = 0; sl < 16; ++sl){
        const float p = P[sl * 128 + t];
        acc[sl][0] += p * e0; acc[sl][1] += p * e1;
      }
    }
    #pragma unroll
    for (int sl = 0; sl < 16; ++sl){
      const int mm = (s0 + sl) * 32 + b;
      uint u = ((uint)f2bf(acc[sl][1]) << 16) | (uint)f2bf(acc[sl][0]);
      *(uint*)(Ac + (size_t)mm * 1024 + h0) = u;
    }
  }
}

// ---------------- fused log-softmax finish: lse from partials, bf16 logits -> f32 out ----------------
// bf16 logits live in the SECOND half of each f32 row slot of d_out (ushort idx row*64000+32000).
// Stage the whole bf16 row to LDS before any f32 write -> in-slot expansion is race-free.
__global__ __launch_bounds__(256) void k_sub(float* __restrict__ out,
                                             const float* __restrict__ pM, const float* __restrict__ pL){
  __shared__ float slse;
  __shared__ __align__(16) ushort rowb[VD];   // 64 KB
  const int row = blockIdx.x;
  const int tid = threadIdx.x;
  const ushort* src = (const ushort*)out + (size_t)row * 64000 + 32000;
  for (int i = tid; i < VD / 8; i += 256)
    *(uint4*)(rowb + (i << 3)) = *(const uint4*)(src + (i << 3));
  if (tid < 64){
    float m = -1e30f, l = 0.f;
    for (int i = tid; i < 250; i += 64){
      float m2 = pM[(size_t)row * 256 + i], l2 = pL[(size_t)row * 256 + i];
      float nm = fmaxf(m, m2);
      l = l * __expf(m - nm) + l2 * __expf(m2 - nm);
      m = nm;
    }
    #pragma unroll
    for (int off = 32; off; off >>= 1){
      float m2 = __shfl_xor(m, off), l2 = __shfl_xor(l, off);
      float nm = fmaxf(m, m2);
      l = l * __expf(m - nm) + l2 * __expf(m2 - nm);
      m = nm;
    }
    if (tid == 0) slse = m + __logf(l);
  }
  __syncthreads();                            // staging complete + slse ready
  const float s = slse;
  float* p = out + (size_t)row * VD;
  for (int i = tid; i < VD / 8; i += 256){
    uint4 v = *(const uint4*)(rowb + (i << 3));
    f32x4 o0, o1;
    o0[0] = bfl(v.x) - s; o0[1] = bfh(v.x) - s; o0[2] = bfl(v.y) - s; o0[3] = bfh(v.y) - s;
    o1[0] = bfl(v.z) - s; o1[1] = bfh(v.z) - s; o1[2] = bfl(v.w) - s; o1[3] = bfh(v.w) - s;
    *(f32x4*)(p + (i << 3)) = o0;
    *(f32x4*)(p + (i << 3) + 4) = o1;
  }
}

extern "C" void kernel_launch(void* const* d_in, const int* in_sizes, int n_in,
                              void* d_out, int out_size, void* d_ws, size_t ws_size,
                              hipStream_t stream){
  const int*   enc_in  = (const int*)d_in[0];
  const int*   dec_in  = (const int*)d_in[1];
  const float* enc_emb = (const float*)d_in[2];
  const float* dec_emb = (const float*)d_in[3];
  const float* WihE    = (const float*)d_in[4];
  const float* WhhE    = (const float*)d_in[5];
  const float* WihD    = (const float*)d_in[6];
  const float* WhhD    = (const float*)d_in[7];
  const float* We      = (const float*)d_in[8];
  const float* be      = (const float*)d_in[9];
  const float* Wd      = (const float*)d_in[10];
  const float* bd      = (const float*)d_in[11];
  const float* outW    = (const float*)d_in[12];
  const float* outb    = (const float*)d_in[13];
  float* out = (float*)d_out;

  char* ws = (char*)d_ws;
  size_t off = 0;
  auto alloc = [&](size_t bytes){ void* p = ws + off; off += (bytes + 255) & ~(size_t)255; return p; };
  ushort* xe    = (ushort*)alloc((size_t)MM * HH * 2);
  ushort* xd    = (ushort*)alloc((size_t)MM * HH * 2);
  ushort* WihEb = (ushort*)alloc((size_t)2048 * 512 * 2);
  ushort* WihDb = (ushort*)alloc((size_t)2048 * 512 * 2);
  ushort* Bc    = (ushort*)alloc((size_t)512 * 1024 * 2);
  float*  bsum  = (float*)alloc(512 * 4);
  ushort* outWb = (ushort*)alloc((size_t)VD * HH * 2);
  ushort* encO  = (ushort*)alloc((size_t)MM * HH * 2);
  ushort* decO  = (ushort*)alloc((size_t)MM * HH * 2);
  u64*    hbuf  = (u64*)alloc(8192 * 8);               // 64 KB tagged-bf16 double buffer
  ushort* Ac    = (ushort*)alloc((size_t)MM * 1024 * 2);
  ushort* hid   = (ushort*)alloc((size_t)MM * HH * 2);
  float*  pbufM = (float*)alloc((size_t)MM * 256 * 4); // 4 MB
  float*  pbufL = (float*)alloc((size_t)MM * 256 * 4); // 4 MB
  // Gin buffers (67 MB) live in d_out-as-scratch: dead before logits GEMM writes d_out.
  float* GinE = out;
  float* GinD = out + (size_t)MM * 2048;
  // bf16 logits scratch: second half of each f32 row slot of d_out (row*64000+32000 ushorts).
  ushort* logb = (ushort*)out + 32000;

  k_init<<<dim3(32), dim3(256), 0, stream>>>(hbuf);
  k_cvt<<<dim3(1024), dim3(256), 0, stream>>>(WihE, WihEb, 2048 * 512 / 4);
  k_cvt<<<dim3(1024), dim3(256), 0, stream>>>(WihD, WihDb, 2048 * 512 / 4);
  k_cvt<<<dim3(2048), dim3(256), 0, stream>>>(outW, outWb, VD * HH / 4);
  k_concatB<<<dim3(512), dim3(128), 0, stream>>>(We, Wd, Bc);
  k_bsum<<<dim3(2), dim3(256), 0, stream>>>(be, bd, bsum);
  k_embed<<<dim3(MM), dim3(128), 0, stream>>>(enc_in, enc_emb, xe);
  k_embed<<<dim3(MM), dim3(128), 0, stream>>>(dec_in, dec_emb, xd);
  // input projections: Gin = x @ Wih^T   [4096,512]x[2048,512]^T
  k_gemm<false, false, false, false><<<dim3(16, 32), dim3(256), 0, stream>>>(xe, WihEb, (const float*)nullptr, GinE, MM, 2048, 512, 2048, nullptr, nullptr);
  k_gemm<false, false, false, false><<<dim3(16, 32), dim3(256), 0, stream>>>(xd, WihDb, (const float*)nullptr, GinD, MM, 2048, 512, 2048, nullptr, nullptr);
  // both LSTMs (persistent, coalesced tag-in-data exchange, MFMA recurrence, weights in LDS)
  k_lstm<<<dim3(NLB), dim3(512), 0, stream>>>(GinE, GinD, WhhE, WhhD, hbuf, encO, decO, Ac);
  // attention -> ctx into Ac[:, 0:512] (dec h already in Ac[:, 512:1024])
  k_attn<<<dim3(256), dim3(256), 0, stream>>>(encO, decO, Ac);
  // hidden = tanh([ctx|dec] @ [We|Wd]^T + (be+bd))   K=1024 -> bf16
  k_gemm<true, true, true, false><<<dim3(4, 32), dim3(256), 0, stream>>>(Ac, Bc, bsum, hid, MM, 512, 1024, 512, nullptr, nullptr);
  // logits = hidden @ outW^T + out_b -> bf16 into row-slot tails of d_out, + per-tile lse partials
  k_gemm<true, false, true, true><<<dim3(250, 32), dim3(256), 0, stream>>>(hid, outWb, outb, logb, MM, VD, 512, 64000, pbufM, pbufL);
  // log-softmax finish: lse from partials + bf16 -> f32 expansion (in-slot, LDS-staged)
  k_sub<<<dim3(MM), dim3(256), 0, stream>>>(out, pbufM, pbufL);
}